// Round 6
// baseline (73.104 us; speedup 1.0000x reference)
//
#include <hip/hip_runtime.h>

#define D 128
#define NS 16
#define BATCH 16384
#define TILE 64
#define CHUNK 1024

typedef __attribute__((ext_vector_type(8))) short short8;
typedef __attribute__((ext_vector_type(4))) float f32x4;

__device__ __forceinline__ unsigned short f2bf(float f) {
  unsigned u = __builtin_bit_cast(unsigned, f);
  u += 0x7FFFu + ((u >> 16) & 1u);   // round-to-nearest-even
  return (unsigned short)(u >> 16);
}

__device__ __forceinline__ uint4 pack8(float4 a, float4 b) {
  unsigned short p[8];
  p[0] = f2bf(a.x); p[1] = f2bf(a.y); p[2] = f2bf(a.z); p[3] = f2bf(a.w);
  p[4] = f2bf(b.x); p[5] = f2bf(b.y); p[6] = f2bf(b.z); p[7] = f2bf(b.w);
  return *(const uint4*)p;
}

// ---------------------------------------------------------------------------
// R6 = R5 (reg-resident bf16 B-frags, XOR-swizzled XH, single kernel) with
// the per-block fixed cost amortized 2x:
//  - CHUNK 1024 -> 256 blocks (1/CU). Aggregate weight gather halves
//    (32MB, ~0.25M VMEM instr); per-row fixed cost halves.
//  - cnt ~ Bin(1024,1/16) = 64 +- 7.7; TILE=64 with block-uniform per-stripe
//    skip guards (i0 + ti*16 < cnt) so the ~50%-probable second pass costs
//    ~1/4 of a full tile, not a full one.
//  - XCD locality kept: state = b&15, XCD = b&7 -> all 16 blocks of a state
//    share one XCD's L2 for its 128KB of weights.
//  MFMA 16x16x32 bf16 layouts (HW-verified):
//    A: A[m=lane&15][k=(lane>>4)*8+j]   B: B[k=(lane>>4)*8+j][n=lane&15]
//    C/D: col=lane&15, row=(lane>>4)*4+reg
//  Wave w: all 64 tile rows, cols w*32..+31. LDS: XH 16K + rowlist 4K = 20.2K.
// ---------------------------------------------------------------------------
__global__ __launch_bounds__(256, 2) void ssm_fused(
    const float* __restrict__ x,
    const int* __restrict__ sidx,
    const float* __restrict__ A_all,
    const float* __restrict__ C_all,
    float* __restrict__ out) {
  __shared__ unsigned short XH[TILE * D];   // [row][chunk ^ (row&15)][8]
  __shared__ int rowlist[CHUNK];
  __shared__ int wcnt[16];

  const int b = blockIdx.x;
  const int s = b & 15;                 // XCD = b&7: one XCD per state
  const int c0 = (b >> 4) * CHUNK;
  const int tid = threadIdx.x;
  const int lane = tid & 63, w = tid >> 6;
  const int l15 = lane & 15, quad = lane >> 4;

  // ---- 1. scan chunk (loads first; ballots overlap the weight loads) ----
  const int v0 = sidx[c0 + tid];
  const int v1 = sidx[c0 + 256 + tid];
  const int v2 = sidx[c0 + 512 + tid];
  const int v3 = sidx[c0 + 768 + tid];

  // ---- 2. B-fragments for BOTH phases, direct fp32 -> bf16 regs ----
  // frag (kb,nb): elems A[k = kb*32 + quad*8 + j][col = w*32 + nb*16 + l15]
  short8 aW[4][2], cW[4][2];
  {
    const size_t wb = (size_t)s * D * D;
    const int col = w * 32 + l15;
#pragma unroll
    for (int kb = 0; kb < 4; kb++)
#pragma unroll
      for (int nb = 0; nb < 2; nb++) {
        const float* pA =
            A_all + wb + (size_t)(kb * 32 + quad * 8) * D + col + nb * 16;
        const float* pC =
            C_all + wb + (size_t)(kb * 32 + quad * 8) * D + col + nb * 16;
        unsigned short ta[8], tc[8];
#pragma unroll
        for (int j = 0; j < 8; j++) {
          ta[j] = f2bf(pA[j * D]);
          tc[j] = f2bf(pC[j * D]);
        }
        aW[kb][nb] = *(const short8*)ta;
        cW[kb][nb] = *(const short8*)tc;
      }
  }

  // ---- ballot compaction (4 groups x 4 waves, order j = g*4 + w) ----
  const unsigned long long lanelt = (1ull << lane) - 1ull;
  const unsigned long long m0 = __ballot(v0 == s);
  const unsigned long long m1 = __ballot(v1 == s);
  const unsigned long long m2 = __ballot(v2 == s);
  const unsigned long long m3 = __ballot(v3 == s);
  if (lane == 0) {
    wcnt[w] = (int)__popcll(m0);
    wcnt[4 + w] = (int)__popcll(m1);
    wcnt[8 + w] = (int)__popcll(m2);
    wcnt[12 + w] = (int)__popcll(m3);
  }
  __syncthreads();
  int preg[4], cnt = 0;
#pragma unroll
  for (int g = 0; g < 4; g++) {
    preg[g] = cnt;
    int sub = 0;
#pragma unroll
    for (int ww = 0; ww < 4; ww++) {
      const int c = wcnt[g * 4 + ww];
      if (ww < w) sub += c;
      cnt += c;
    }
    preg[g] += sub;
  }
  if (v0 == s) rowlist[preg[0] + (int)__popcll(m0 & lanelt)] = c0 + tid;
  if (v1 == s) rowlist[preg[1] + (int)__popcll(m1 & lanelt)] = c0 + 256 + tid;
  if (v2 == s) rowlist[preg[2] + (int)__popcll(m2 & lanelt)] = c0 + 512 + tid;
  if (v3 == s) rowlist[preg[3] + (int)__popcll(m3 & lanelt)] = c0 + 768 + tid;
  if (cnt == 0) return;  // block-uniform

  // ---- 3. MFMA tiles (E[passes] ~ 1.5; spill pass stripe-skipped) ----
#pragma unroll 1
  for (int i0 = 0; i0 < cnt; i0 += TILE) {
    __syncthreads();  // rowlist ready (pass 0) / prior pass XH reads done

    // stripe-valid flags (block-uniform: cnt, i0 uniform)
    const bool tv1 = (i0 + 16 < cnt), tv2 = (i0 + 32 < cnt), tv3 = (i0 + 48 < cnt);

    // gather 64 X rows (4 threads/row, fp32 -> bf16), XOR-swizzled chunks
    {
      const int r = tid >> 2, q = tid & 3;
      const int rid = (i0 + r < cnt) ? rowlist[i0 + r] : -1;
      if (rid >= 0) {
        const float4* src = (const float4*)(x + (size_t)rid * D + q * 32);
#pragma unroll
        for (int i = 0; i < 4; i++) {
          float4 va = src[2 * i];
          float4 vb = src[2 * i + 1];
          *(uint4*)&XH[r * D + (((q * 4 + i) ^ (r & 15)) << 3)] = pack8(va, vb);
        }
      } else {
        uint4 z = {0, 0, 0, 0};
#pragma unroll
        for (int i = 0; i < 4; i++)
          *(uint4*)&XH[r * D + (((q * 4 + i) ^ (r & 15)) << 3)] = z;
      }
    }
    __syncthreads();  // X ready

    // phase 1: acc = X @ A ; wave w: all 64 rows, cols w*32..+31
    f32x4 acc[4][2];
#pragma unroll
    for (int ti = 0; ti < 4; ti++) {
      acc[ti][0] = (f32x4){0.f, 0.f, 0.f, 0.f};
      acc[ti][1] = (f32x4){0.f, 0.f, 0.f, 0.f};
    }
#pragma unroll
    for (int kb = 0; kb < 4; kb++) {
      short8 aF[4];
#pragma unroll
      for (int ti = 0; ti < 4; ti++) {
        if (ti == 1 && !tv1) continue;
        if (ti == 2 && !tv2) continue;
        if (ti == 3 && !tv3) continue;
        aF[ti] = *(const short8*)&XH[(ti * 16 + l15) * D +
                                     (((kb * 4 + quad) ^ l15) << 3)];
      }
#pragma unroll
      for (int ti = 0; ti < 4; ti++) {
        if (ti == 1 && !tv1) continue;
        if (ti == 2 && !tv2) continue;
        if (ti == 3 && !tv3) continue;
        acc[ti][0] = __builtin_amdgcn_mfma_f32_16x16x32_bf16(aF[ti], aW[kb][0],
                                                             acc[ti][0], 0, 0, 0);
        acc[ti][1] = __builtin_amdgcn_mfma_f32_16x16x32_bf16(aF[ti], aW[kb][1],
                                                             acc[ti][1], 0, 0, 0);
      }
    }
    __syncthreads();  // all phase-1 XH(X) reads done (XH reused for H)

    // H = relu(acc) -> XH, swizzle-consistent scalar writes
#pragma unroll
    for (int ti = 0; ti < 4; ti++) {
      if (ti == 1 && !tv1) continue;
      if (ti == 2 && !tv2) continue;
      if (ti == 3 && !tv3) continue;
#pragma unroll
      for (int nb = 0; nb < 2; nb++)
#pragma unroll
        for (int rr = 0; rr < 4; rr++) {
          float v = acc[ti][nb][rr];
          const int row = ti * 16 + quad * 4 + rr;
          const int ch = (w * 4 + nb * 2 + (l15 >> 3)) ^ (quad * 4 + rr);
          XH[row * D + (ch << 3) + (l15 & 7)] = f2bf(v > 0.f ? v : 0.f);
        }
    }
    __syncthreads();  // H ready

    // phase 2: out = H @ C
#pragma unroll
    for (int ti = 0; ti < 4; ti++) {
      acc[ti][0] = (f32x4){0.f, 0.f, 0.f, 0.f};
      acc[ti][1] = (f32x4){0.f, 0.f, 0.f, 0.f};
    }
#pragma unroll
    for (int kb = 0; kb < 4; kb++) {
      short8 aF[4];
#pragma unroll
      for (int ti = 0; ti < 4; ti++) {
        if (ti == 1 && !tv1) continue;
        if (ti == 2 && !tv2) continue;
        if (ti == 3 && !tv3) continue;
        aF[ti] = *(const short8*)&XH[(ti * 16 + l15) * D +
                                     (((kb * 4 + quad) ^ l15) << 3)];
      }
#pragma unroll
      for (int ti = 0; ti < 4; ti++) {
        if (ti == 1 && !tv1) continue;
        if (ti == 2 && !tv2) continue;
        if (ti == 3 && !tv3) continue;
        acc[ti][0] = __builtin_amdgcn_mfma_f32_16x16x32_bf16(aF[ti], cW[kb][0],
                                                             acc[ti][0], 0, 0, 0);
        acc[ti][1] = __builtin_amdgcn_mfma_f32_16x16x32_bf16(aF[ti], cW[kb][1],
                                                             acc[ti][1], 0, 0, 0);
      }
    }

    // scatter stores (fp32; 16 consecutive lanes -> 64B segments)
#pragma unroll
    for (int ti = 0; ti < 4; ti++) {
      if (ti == 1 && !tv1) continue;
      if (ti == 2 && !tv2) continue;
      if (ti == 3 && !tv3) continue;
#pragma unroll
      for (int rr = 0; rr < 4; rr++) {
        const int rl = i0 + ti * 16 + quad * 4 + rr;
        if (rl < cnt) {
          float* orow = out + (size_t)rowlist[rl] * D + w * 32 + l15;
          orow[0] = acc[ti][0][rr];
          orow[16] = acc[ti][1][rr];
        }
      }
    }
  }
}

extern "C" void kernel_launch(void* const* d_in, const int* in_sizes, int n_in,
                              void* d_out, int out_size, void* d_ws, size_t ws_size,
                              hipStream_t stream) {
  const float* x = (const float*)d_in[0];
  const int* sidx = (const int*)d_in[1];
  const float* A_all = (const float*)d_in[2];
  const float* C_all = (const float*)d_in[3];
  float* out = (float*)d_out;

  ssm_fused<<<BATCH / CHUNK * NS, 256, 0, stream>>>(x, sidx, A_all, C_all, out);
}

// Round 7
// 71.653 us; speedup vs baseline: 1.0202x; 1.0202x over previous
//
#include <hip/hip_runtime.h>

#define D 128
#define NS 16
#define BATCH 16384
#define TILE 64
#define CHUNK 512

typedef __attribute__((ext_vector_type(8))) short short8;
typedef __attribute__((ext_vector_type(4))) float f32x4;

__device__ __forceinline__ unsigned short f2bf(float f) {
  unsigned u = __builtin_bit_cast(unsigned, f);
  u += 0x7FFFu + ((u >> 16) & 1u);   // round-to-nearest-even
  return (unsigned short)(u >> 16);
}

__device__ __forceinline__ uint4 pack8(float4 a, float4 b) {
  unsigned short p[8];
  p[0] = f2bf(a.x); p[1] = f2bf(a.y); p[2] = f2bf(a.z); p[3] = f2bf(a.w);
  p[4] = f2bf(b.x); p[5] = f2bf(b.y); p[6] = f2bf(b.z); p[7] = f2bf(b.w);
  return *(const uint4*)p;
}

// ---------------------------------------------------------------------------
// R7 = R5 (best: 512 blocks, CHUNK 512, reg-resident bf16 B-frags,
// XOR-swizzled XH) at DOUBLE the wave count, constant aggregate traffic:
//  - 512 threads/block (8 waves), same 512-block grid -> 4 waves/SIMD
//    (R5 was 2). Weight loads 64/thread (was 128); per-wave MFMA 16/phase
//    (was 32); totals identical. Pure latency-hiding move:
//    R2/R3 doubled blocks (doubling weight traffic) and regressed; this
//    doubles waves at constant traffic.
//  - wave w owns cols w*16..+15 (8 disjoint 16-col slices).
//  MFMA 16x16x32 bf16 layouts (HW-verified):
//    A: A[m=lane&15][k=(lane>>4)*8+j]   B: B[k=(lane>>4)*8+j][n=lane&15]
//    C/D: col=lane&15, row=(lane>>4)*4+reg
//  LDS: XH 16K + rowlist 2K + wcnt = 18.1K (2 blocks/CU -> 36K, fine).
//  VGPR: aW 16 + cW 16 + acc 16 + aF 16 + addr ~ <128 -> 4 waves/SIMD ok.
// ---------------------------------------------------------------------------
__global__ __launch_bounds__(512, 4) void ssm_fused(
    const float* __restrict__ x,
    const int* __restrict__ sidx,
    const float* __restrict__ A_all,
    const float* __restrict__ C_all,
    float* __restrict__ out) {
  __shared__ unsigned short XH[TILE * D];   // [row][chunk ^ (row&15)][8]
  __shared__ int rowlist[CHUNK];
  __shared__ int wcnt[8];

  const int b = blockIdx.x;
  const int s = (b & 7) | (((b >> 3) & 1) << 3);  // same-state blocks same XCD
  const int c0 = (b >> 4) * CHUNK;
  const int tid = threadIdx.x;
  const int lane = tid & 63, w = tid >> 6;        // w in [0,8)
  const int l15 = lane & 15, quad = lane >> 4;

  // ---- 1. scan chunk: 512 threads cover CHUNK with one load each ----
  const int v0 = sidx[c0 + tid];

  // ---- 2. B-fragments for BOTH phases, direct fp32 -> bf16 regs ----
  // frag kb: elems A[k = kb*32 + quad*8 + j][col = w*16 + l15]
  short8 aW[4], cW[4];
  {
    const size_t wb = (size_t)s * D * D;
    const int col = w * 16 + l15;
#pragma unroll
    for (int kb = 0; kb < 4; kb++) {
      const float* pA = A_all + wb + (size_t)(kb * 32 + quad * 8) * D + col;
      const float* pC = C_all + wb + (size_t)(kb * 32 + quad * 8) * D + col;
      unsigned short ta[8], tc[8];
#pragma unroll
      for (int j = 0; j < 8; j++) {
        ta[j] = f2bf(pA[j * D]);
        tc[j] = f2bf(pC[j * D]);
      }
      aW[kb] = *(const short8*)ta;
      cW[kb] = *(const short8*)tc;
    }
  }

  // ---- ballot compaction (8 waves) ----
  const unsigned long long lanelt = (1ull << lane) - 1ull;
  const unsigned long long m0 = __ballot(v0 == s);
  if (lane == 0) wcnt[w] = (int)__popcll(m0);
  __syncthreads();  // wcnt ready
  int pre = 0, cnt = 0;
#pragma unroll
  for (int ww = 0; ww < 8; ww++) {
    const int c = wcnt[ww];
    if (ww < w) pre += c;
    cnt += c;
  }
  if (v0 == s) rowlist[pre + (int)__popcll(m0 & lanelt)] = c0 + tid;
  if (cnt == 0) return;  // block-uniform

  // ---- 3. MFMA tiles (E[cnt]=32: one 64-row pass ~always) ----
#pragma unroll 1
  for (int i0 = 0; i0 < cnt; i0 += TILE) {
    __syncthreads();  // rowlist ready (pass 0) / prior pass XH reads done

    // gather 64 X rows (8 threads/row, 16 elems each), XOR-swizzled chunks
    {
      const int r = tid >> 3, q8 = tid & 7;
      const int rid = (i0 + r < cnt) ? rowlist[i0 + r] : -1;
      const int cA = q8 * 2, cB = q8 * 2 + 1;
      uint4* dA = (uint4*)&XH[r * D + ((cA ^ (r & 15)) << 3)];
      uint4* dB = (uint4*)&XH[r * D + ((cB ^ (r & 15)) << 3)];
      if (rid >= 0) {
        const float4* src = (const float4*)(x + (size_t)rid * D + q8 * 16);
        *dA = pack8(src[0], src[1]);
        *dB = pack8(src[2], src[3]);
      } else {
        uint4 z = {0, 0, 0, 0};
        *dA = z;
        *dB = z;
      }
    }
    __syncthreads();  // X ready

    // phase 1: acc = X @ A ; wave w: all 64 rows, cols w*16..+15
    f32x4 acc[4];
#pragma unroll
    for (int ti = 0; ti < 4; ti++) acc[ti] = (f32x4){0.f, 0.f, 0.f, 0.f};
#pragma unroll
    for (int kb = 0; kb < 4; kb++) {
      short8 aF[4];
#pragma unroll
      for (int ti = 0; ti < 4; ti++)
        aF[ti] = *(const short8*)&XH[(ti * 16 + l15) * D +
                                     (((kb * 4 + quad) ^ l15) << 3)];
#pragma unroll
      for (int ti = 0; ti < 4; ti++)
        acc[ti] = __builtin_amdgcn_mfma_f32_16x16x32_bf16(aF[ti], aW[kb],
                                                          acc[ti], 0, 0, 0);
    }
    __syncthreads();  // all phase-1 XH(X) reads done (XH reused for H)

    // H = relu(acc) -> XH, swizzle-consistent scalar writes
#pragma unroll
    for (int ti = 0; ti < 4; ti++)
#pragma unroll
      for (int rr = 0; rr < 4; rr++) {
        float v = acc[ti][rr];
        const int row = ti * 16 + quad * 4 + rr;
        const int ch = (w * 2 + (l15 >> 3)) ^ (quad * 4 + rr);
        XH[row * D + (ch << 3) + (l15 & 7)] = f2bf(v > 0.f ? v : 0.f);
      }
    __syncthreads();  // H ready

    // phase 2: out = H @ C
#pragma unroll
    for (int ti = 0; ti < 4; ti++) acc[ti] = (f32x4){0.f, 0.f, 0.f, 0.f};
#pragma unroll
    for (int kb = 0; kb < 4; kb++) {
      short8 aF[4];
#pragma unroll
      for (int ti = 0; ti < 4; ti++)
        aF[ti] = *(const short8*)&XH[(ti * 16 + l15) * D +
                                     (((kb * 4 + quad) ^ l15) << 3)];
#pragma unroll
      for (int ti = 0; ti < 4; ti++)
        acc[ti] = __builtin_amdgcn_mfma_f32_16x16x32_bf16(aF[ti], cW[kb],
                                                          acc[ti], 0, 0, 0);
    }

    // scatter stores (fp32; 16 consecutive lanes -> 64B segments)
#pragma unroll
    for (int ti = 0; ti < 4; ti++)
#pragma unroll
      for (int rr = 0; rr < 4; rr++) {
        const int rl = i0 + ti * 16 + quad * 4 + rr;
        if (rl < cnt) {
          out[(size_t)rowlist[rl] * D + w * 16 + l15] = acc[ti][rr];
        }
      }
  }
}

extern "C" void kernel_launch(void* const* d_in, const int* in_sizes, int n_in,
                              void* d_out, int out_size, void* d_ws, size_t ws_size,
                              hipStream_t stream) {
  const float* x = (const float*)d_in[0];
  const int* sidx = (const int*)d_in[1];
  const float* A_all = (const float*)d_in[2];
  const float* C_all = (const float*)d_in[3];
  float* out = (float*)d_out;

  ssm_fused<<<BATCH / CHUNK * NS, 512, 0, stream>>>(x, sidx, A_all, C_all, out);
}